// Round 1
// baseline (1567.530 us; speedup 1.0000x reference)
//
#include <hip/hip_runtime.h>
#include <hip/hip_bf16.h>

// Sparse BasicBlock: conv1 -> BN1 -> ReLU -> conv2 -> BN2 -> +x -> ReLU
// N=262144 nodes, C=64 channels, K=27 offsets, P=131072 pairs/offset.
// Strategy: per-k gather+GEMM(bf16 MFMA)+scatter(fp32 atomics); BN fused.

#define NNODES 262144
#define NC 64
#define NK 27
#define NP 131072
#define EPSV 1e-5f
#define TILE 64        // pairs per LDS tile
#define TPB 8          // tiles per block

typedef float f32x4 __attribute__((ext_vector_type(4)));
typedef __bf16 bf16x8 __attribute__((ext_vector_type(8)));

// ---------------------------------------------------------------- prep: W -> bf16 transposed Wt[k][co][ci]
__global__ void prep_w(const float* __restrict__ W, __bf16* __restrict__ Wt) {
    int i = blockIdx.x * 256 + threadIdx.x;
    if (i >= NK * NC * NC) return;
    int k  = i >> 12;
    int n  = (i >> 6) & 63;   // co
    int ci = i & 63;
    Wt[i] = (__bf16)W[k * 4096 + ci * 64 + n];
}

// ---------------------------------------------------------------- conv: out[ok[p]] += X[ik[p]] @ Wk
// BN=true: input transform y = relu(x*s + t) applied during gather (fused BN1+ReLU).
template <bool BN>
__global__ __launch_bounds__(256)
void conv_kernel(const float* __restrict__ X,
                 const __bf16* __restrict__ Wt,
                 const int* __restrict__ in_idx,
                 const int* __restrict__ out_idx,
                 const float* __restrict__ st,
                 float* __restrict__ Out) {
    const int k    = blockIdx.y;
    const int tid  = threadIdx.x;
    const int wave = tid >> 6;
    const int lane = tid & 63;
    const int l15  = lane & 15;
    const int l4   = lane >> 4;

    __shared__ __align__(16) __bf16 As[64 * 64];  // XOR-swizzled A tile (64 rows x 64 cols bf16)
    __shared__ int oks[TILE];
    __shared__ float s_s[64], s_t[64];

    if (BN && tid < 64) { s_s[tid] = st[tid]; s_t[tid] = st[64 + tid]; }

    // B fragments in registers: wave computes rows [wave*16, wave*16+16), all 4 n-tiles.
    // lane l holds B[k=ks*32+8*(l>>4)+j][n=nt*16+(l&15)] = Wt[k_off][n][kk..kk+7]
    bf16x8 bfrag[4][2];
    const __bf16* Wk = Wt + k * 4096;
#pragma unroll
    for (int nt = 0; nt < 4; ++nt)
#pragma unroll
        for (int ks = 0; ks < 2; ++ks)
            bfrag[nt][ks] = *(const bf16x8*)(Wk + (nt * 16 + l15) * 64 + ks * 32 + l4 * 8);

    const int* ik = in_idx + k * NP;
    const int* ok = out_idx + k * NP;

    const int r = tid >> 2;   // row in tile (4 threads per row)
    const int q = tid & 3;    // 16-col segment
    char* Abase = (char*)As;
    const int rb = wave * 16;

    __syncthreads();

    int p0 = (blockIdx.x * TPB) * TILE;
    for (int t = 0; t < TPB; ++t, p0 += TILE) {
        if (tid < TILE) oks[tid] = ok[p0 + tid];
        // ---- gather 64 rows (fp32), optional BN+ReLU, convert bf16, swizzled LDS store
        const float* xr = X + ik[p0 + r] * 64 + q * 16;
        f32x4 v0 = *(const f32x4*)(xr + 0);
        f32x4 v1 = *(const f32x4*)(xr + 4);
        f32x4 v2 = *(const f32x4*)(xr + 8);
        f32x4 v3 = *(const f32x4*)(xr + 12);
        float vals[16];
        *(f32x4*)&vals[0]  = v0;
        *(f32x4*)&vals[4]  = v1;
        *(f32x4*)&vals[8]  = v2;
        *(f32x4*)&vals[12] = v3;
        if (BN) {
            const int cb = q * 16;
#pragma unroll
            for (int j = 0; j < 16; ++j)
                vals[j] = fmaxf(fmaf(vals[j], s_s[cb + j], s_t[cb + j]), 0.0f);
        }
        bf16x8 c0, c1;
#pragma unroll
        for (int j = 0; j < 8; ++j) { c0[j] = (__bf16)vals[j]; c1[j] = (__bf16)vals[8 + j]; }
        // swizzle: 16B chunk index XOR (row&7) — kills the [row][128B] b128 bank conflict
        *(bf16x8*)(Abase + r * 128 + (((2 * q)     ^ (r & 7)) << 4)) = c0;
        *(bf16x8*)(Abase + r * 128 + (((2 * q + 1) ^ (r & 7)) << 4)) = c1;
        __syncthreads();

        // ---- MFMA: 16x64 rows per wave, K=64 in 2 steps
        f32x4 acc[4];
#pragma unroll
        for (int nt = 0; nt < 4; ++nt)
#pragma unroll
            for (int j = 0; j < 4; ++j) acc[nt][j] = 0.0f;
#pragma unroll
        for (int ks = 0; ks < 2; ++ks) {
            const int row = rb + l15;
            bf16x8 a = *(const bf16x8*)(Abase + row * 128 + ((((ks << 2) + l4) ^ (row & 7)) << 4));
#pragma unroll
            for (int nt = 0; nt < 4; ++nt)
                acc[nt] = __builtin_amdgcn_mfma_f32_16x16x32_bf16(a, bfrag[nt][ks], acc[nt], 0, 0, 0);
        }

        // ---- scatter-add: D layout col=lane&15, row=(lane>>4)*4+reg
#pragma unroll
        for (int rg = 0; rg < 4; ++rg) {
            const int rr = rb + l4 * 4 + rg;
            float* orow = Out + (size_t)oks[rr] * 64;
#pragma unroll
            for (int nt = 0; nt < 4; ++nt)
                unsafeAtomicAdd(orow + nt * 16 + l15, acc[nt][rg]);
        }
        __syncthreads();
    }
}

// ---------------------------------------------------------------- BN column stats: sums[c]=sum, sums[64+c]=sumsq
__global__ __launch_bounds__(256)
void bn_stats(const float* __restrict__ H, float* __restrict__ sums) {
    const int c    = threadIdx.x & 63;
    const int slot = threadIdx.x >> 6;
    float s = 0.0f, s2 = 0.0f;
    for (int row = blockIdx.x * 4 + slot; row < NNODES; row += gridDim.x * 4) {
        float v = H[row * 64 + c];
        s += v;
        s2 += v * v;
    }
    __shared__ float red[8][64];
    red[slot][c]     = s;
    red[4 + slot][c] = s2;
    __syncthreads();
    if (slot == 0) {
        s  = red[0][c] + red[1][c] + red[2][c] + red[3][c];
        s2 = red[4][c] + red[5][c] + red[6][c] + red[7][c];
        unsafeAtomicAdd(&sums[c], s);
        unsafeAtomicAdd(&sums[64 + c], s2);
    }
}

// ---------------------------------------------------------------- BN params: st[c]=scale, st[64+c]=shift
__global__ void bn_params(const float* __restrict__ sums, const float* __restrict__ gamma,
                          const float* __restrict__ beta, float* __restrict__ st) {
    int c = threadIdx.x;
    const float inv = 1.0f / (float)NNODES;
    float mean = sums[c] * inv;
    float var  = sums[64 + c] * inv - mean * mean;
    float s    = gamma[c] * rsqrtf(var + EPSV);
    st[c]      = s;
    st[64 + c] = beta[c] - mean * s;
}

// ---------------------------------------------------------------- final: out = relu(h2*s + t + x), in place
__global__ __launch_bounds__(256)
void final_kernel(float* __restrict__ Out, const float* __restrict__ X, const float* __restrict__ st) {
    __shared__ float s_s[64], s_t[64];
    if (threadIdx.x < 64) { s_s[threadIdx.x] = st[threadIdx.x]; s_t[threadIdx.x] = st[64 + threadIdx.x]; }
    __syncthreads();
    int i = blockIdx.x * 256 + threadIdx.x;   // f32x4 index, N*C/4 total
    f32x4 h  = *(f32x4*)(Out + (size_t)i * 4);
    f32x4 xv = *(const f32x4*)(X + (size_t)i * 4);
    const int cb = (i & 15) * 4;
    f32x4 o;
#pragma unroll
    for (int j = 0; j < 4; ++j)
        o[j] = fmaxf(fmaf(h[j], s_s[cb + j], s_t[cb + j]) + xv[j], 0.0f);
    *(f32x4*)(Out + (size_t)i * 4) = o;
}

// ---------------------------------------------------------------- launch
extern "C" void kernel_launch(void* const* d_in, const int* in_sizes, int n_in,
                              void* d_out, int out_size, void* d_ws, size_t ws_size,
                              hipStream_t stream) {
    const float* x      = (const float*)d_in[0];
    const float* W1     = (const float*)d_in[1];
    // d_in[2] = b1: mathematically cancels through BN1 (mean-subtraction) — skipped.
    const float* gamma1 = (const float*)d_in[3];
    const float* beta1  = (const float*)d_in[4];
    const float* W2     = (const float*)d_in[5];
    // d_in[6] = b2: cancels through BN2 — skipped.
    const float* gamma2 = (const float*)d_in[7];
    const float* beta2  = (const float*)d_in[8];
    const int* in_idx   = (const int*)d_in[9];
    const int* out_idx  = (const int*)d_in[10];
    float* out = (float*)d_out;

    char* ws = (char*)d_ws;
    const size_t H1B = (size_t)NNODES * NC * 4;       // 67108864
    float* h1    = (float*)ws;
    float* sums1 = (float*)(ws + H1B);                // 128 f
    float* st1   = sums1 + 128;
    float* sums2 = st1 + 128;
    float* st2   = sums2 + 128;
    __bf16* Wt1  = (__bf16*)(ws + H1B + 4096);
    __bf16* Wt2  = Wt1 + NK * NC * NC;

    hipMemsetAsync(h1, 0, H1B, stream);
    hipMemsetAsync(sums1, 0, 2048, stream);
    hipMemsetAsync(d_out, 0, (size_t)out_size * 4, stream);

    prep_w<<<(NK * NC * NC + 255) / 256, 256, 0, stream>>>(W1, Wt1);
    prep_w<<<(NK * NC * NC + 255) / 256, 256, 0, stream>>>(W2, Wt2);

    dim3 cgrid(NP / TILE / TPB, NK);   // (256, 27)
    conv_kernel<false><<<cgrid, 256, 0, stream>>>(x, Wt1, in_idx, out_idx, nullptr, h1);
    bn_stats<<<1024, 256, 0, stream>>>(h1, sums1);
    bn_params<<<1, 64, 0, stream>>>(sums1, gamma1, beta1, st1);
    conv_kernel<true><<<cgrid, 256, 0, stream>>>(h1, Wt2, in_idx, out_idx, st1, out);
    bn_stats<<<1024, 256, 0, stream>>>(out, sums2);
    bn_params<<<1, 64, 0, stream>>>(sums2, gamma2, beta2, st2);
    final_kernel<<<NNODES * NC / 4 / 256, 256, 0, stream>>>(out, x, st2);
}